// Round 7
// baseline (260.869 us; speedup 1.0000x reference)
//
#include <hip/hip_runtime.h>
#include <stdint.h>

#define HH 80
#define WW 80
#define CC 64
#define BB 32
#define NDIAG (HH + WW - 1)   // 159
#define NINT ((NDIAG + 1) / 2)  // 80 fused intervals
#define SLICE (HH * WW * CC)  // 409600 f16 per (dir,b) scratch slice
#define NCW 6                 // compute waves (stride-15 tiles)
#define STRIDE 15
#define NTHREADS 512          // 6 compute + 2 io waves

typedef _Float16 f16;
typedef _Float16 f16x8 __attribute__((ext_vector_type(8)));
typedef _Float16 f16x4 __attribute__((ext_vector_type(4)));
typedef float floatx4 __attribute__((ext_vector_type(4)));

struct GPtrs { const float* p[8]; };

// ---------------------------------------------------------------------------
// Pre-pass: x[b][c][i][j] (f32) -> xT[((b*H+i)*W+j)*C + c] (f16).
// ---------------------------------------------------------------------------
__global__ __launch_bounds__(256) void xpose_kernel(const float* __restrict__ x,
                                                    f16* __restrict__ xT) {
  const int bi = blockIdx.x;            // b*HH + i
  const int b = bi / HH, i = bi - b * HH;
  __shared__ float tile[WW][CC + 1];    // [j][c], stride 65
  const float* xp = x + ((size_t)(b * CC) * HH + i) * WW;  // + c*(H*W) + j
  for (int idx = threadIdx.x; idx < CC * WW; idx += 256) {
    const int c = idx / WW, j = idx - c * WW;   // consecutive j -> coalesced reads
    tile[j][c] = xp[(size_t)c * (HH * WW) + j];
  }
  __syncthreads();
  f16* op = xT + (size_t)(b * HH + i) * WW * CC;
  for (int idx = threadIdx.x; idx < (WW * CC) / 4; idx += 256) {
    const int j = idx >> 4, m = idx & 15;       // 16 lanes cover one j
    f16x4 v;
    v[0] = (f16)tile[j][m * 4 + 0];
    v[1] = (f16)tile[j][m * 4 + 1];
    v[2] = (f16)tile[j][m * 4 + 2];
    v[3] = (f16)tile[j][m * 4 + 3];
    *(f16x4*)(op + j * CC + m * 4) = v;         // 128B contiguous per 16 lanes
  }
}

// ---------------------------------------------------------------------------
// Main kernel, 2-DIAG FUSED intervals: 128 blocks x 512 threads.
// Interval e computes diags D0=2e, D1=2e+1 between consecutive barriers.
// Waves 0..5 (compute): stride-15 tiles. Wave w computes d0 rows
//   [a_w-1, a_w+15) (1-row overlap with wave w-1 -> identical redundant
//   double-write, benign) then d1 rows [a_w, a_w+15) reading ONLY its own
//   d0 LDS writes (self-sufficient; racy 16th lane masked). x is seeded
//   into MFMA C from registers, global-prefetched one interval ahead
//   (compute waves have ZERO stores -> statically clean vmcnt).
// Waves 6..7 (io): flush the previous interval's two diags from the stable
//   hbuf slots to scratch (4-slot ring keeps them intact).
// ---------------------------------------------------------------------------
__global__ __launch_bounds__(NTHREADS, 1) void dag_kernel(const f16* __restrict__ xT,
                                                          GPtrs g,
                                                          f16* __restrict__ scratch) {
  const int blk = blockIdx.x;   // 0..127
  const int dir = blk >> 5;     // 0:SE 1:NE 2:NW 3:SW
  const int b   = blk & 31;
  const int tid = threadIdx.x;
  const int wv   = tid >> 6;    // 0..7
  const int lane = tid & 63;
  const int l15  = lane & 15;   // compute: cell-in-tile (MFMA n / C-D col)
  const int quad = lane >> 4;   // compute: k-quad / C-D row-quad
  const int cq   = quad * 4;    // C/D channel offset within a 16-block

  const bool fi      = (dir == 1) || (dir == 2);  // flip i
  const bool fj      = (dir == 2) || (dir == 3);  // flip j
  const bool do_relu = (dir != 3);                // SW scan has no ReLU
  const float* __restrict__ gv = g.p[2 * dir];
  const float* __restrict__ gh = g.p[2 * dir + 1];

  // 4-slot diag ring: [slot][s][c]; s = i+1, s=0 bottom guard, s=81 top guard.
  __align__(16) __shared__ f16 hbuf[4][HH + 2][CC + 8];   // 47,232 B
  for (int idx = tid; idx < 4 * (HH + 2) * (CC + 8); idx += NTHREADS)
    (&hbuf[0][0][0])[idx] = (f16)0.0f;

  // A fragments (all 4 channel blocks): A[m][k], m=l15, k=quad*8+jj.
  f16x8 Av[4][2], Ah[4][2];
#pragma unroll
  for (int cb = 0; cb < 4; ++cb) {
    const int row = cb * 16 + l15;
    const float* pv = gv + row * CC;
    const float* ph = gh + row * CC;
#pragma unroll
    for (int jj = 0; jj < 8; ++jj) {
      Av[cb][0][jj] = (f16)pv[quad * 8 + jj];
      Av[cb][1][jj] = (f16)pv[32 + quad * 8 + jj];
      Ah[cb][0][jj] = (f16)ph[quad * 8 + jj];
      Ah[cb][1][jj] = (f16)ph[32 + quad * 8 + jj];
    }
  }

  const f16* const xTb = xT + (size_t)b * SLICE;
  f16* const sbase = scratch + (size_t)blk * SLICE;

  // global cell offset (units of CC) for (diag dd, row r), clamped into range
  auto xoff = [&](int dd, int r) -> int {
    const int lo = max(0, dd - (WW - 1));
    const int hi = min(dd, HH - 1);
    const int rc = min(max(r, lo), hi);
    const int jp = dd - rc;
    const int io1 = fi ? (HH - 1 - rc) : rc;
    const int jo1 = fj ? (WW - 1 - jp) : jp;
    return io1 * WW + jo1;
  };

  // prefetch x for interval e1 (T0: diag 2e1 rows a-1+l15; T1: diag 2e1+1 rows a+l15)
  auto pfetch = [&](int e1, f16x4 (*xv)[4]) {
    const int d0 = 2 * e1;
    const int d1c = min(2 * e1 + 1, NDIAG - 1);
    const int aw = max(0, 2 * e1 + 1 - (HH - 1)) + STRIDE * wv;
    const f16* p0 = xTb + xoff(d0, aw - 1 + l15) * CC + cq;
#pragma unroll
    for (int cb = 0; cb < 4; ++cb) xv[0][cb] = *(const f16x4*)(p0 + cb * 16);
    const f16* p1 = xTb + xoff(d1c, aw + l15) * CC + cq;
#pragma unroll
    for (int cb = 0; cb < 4; ++cb) xv[1][cb] = *(const f16x4*)(p1 + cb * 16);
  };

  // one 16-row MFMA tile: read B from slot sR, D = gamma@B + x, write h to sW
  auto doTile = [&](int sR, int sW, int base, int lo, int hi,
                    const f16x4* xv, bool cut15) {
    const int ip = base + l15;
    const int su = min(max(ip, 0), HH + 1);      // up   (ip-1,.) -> s=ip
    const int sl = min(ip + 1, HH + 1);          // left (ip,.-1) -> s=ip+1
    const f16x8 bu0 = *(const f16x8*)&hbuf[sR][su][quad * 8];
    const f16x8 bu1 = *(const f16x8*)&hbuf[sR][su][32 + quad * 8];
    const f16x8 bl0 = *(const f16x8*)&hbuf[sR][sl][quad * 8];
    const f16x8 bl1 = *(const f16x8*)&hbuf[sR][sl][32 + quad * 8];
    const bool ok = (ip >= lo) && (ip <= hi) && (!cut15 || l15 < 15);
#pragma unroll
    for (int cb = 0; cb < 4; ++cb) {
      floatx4 a;
      a[0] = (float)xv[cb][0]; a[1] = (float)xv[cb][1];
      a[2] = (float)xv[cb][2]; a[3] = (float)xv[cb][3];
      a = __builtin_amdgcn_mfma_f32_16x16x32_f16(Av[cb][0], bu0, a, 0, 0, 0);
      a = __builtin_amdgcn_mfma_f32_16x16x32_f16(Av[cb][1], bu1, a, 0, 0, 0);
      a = __builtin_amdgcn_mfma_f32_16x16x32_f16(Ah[cb][0], bl0, a, 0, 0, 0);
      a = __builtin_amdgcn_mfma_f32_16x16x32_f16(Ah[cb][1], bl1, a, 0, 0, 0);
      float h0 = a[0], h1 = a[1], h2 = a[2], h3 = a[3];
      if (do_relu) {
        h0 = fmaxf(h0, 0.f); h1 = fmaxf(h1, 0.f);
        h2 = fmaxf(h2, 0.f); h3 = fmaxf(h3, 0.f);
      }
      f16x4 hw;
      hw[0] = (f16)h0; hw[1] = (f16)h1; hw[2] = (f16)h2; hw[3] = (f16)h3;
      if (ok) *(f16x4*)&hbuf[sW][ip + 1][cb * 16 + cq] = hw;
    }
  };

  // io: flush one diag's h (stable slot) to scratch; 2 io waves split cells
  const int c8io = (lane & 7) * 8;
  auto flushDiag = [&](int dF) {
    const int lo = max(0, dF - (WW - 1)), hi = min(dF, HH - 1);
    const int wio = wv - NCW;                    // 0..1
#pragma unroll
    for (int k = 0; k < 5; ++k) {
      const int cell = ((k * 2 + wio) << 3) + (lane >> 3);
      if (cell >= lo && cell <= hi) {
        const f16x8 hv = *(const f16x8*)&hbuf[dF & 3][cell + 1][c8io];
        const int jp = dF - cell;
        const int io1 = fi ? (HH - 1 - cell) : cell;
        const int jo1 = fj ? (WW - 1 - jp) : jp;
        *(f16x8*)(sbase + (io1 * WW + jo1) * CC + c8io) = hv;  // 128B/8 lanes
      }
    }
  };

  f16x4 xc[2][4], xn[2][4];
  if (wv < NCW) pfetch(0, xc);

  __syncthreads();  // zero-init + A-frag loads settled; one-time full drain

  for (int e = 0; e < NINT; ++e) {
    const int D0 = 2 * e, D1 = 2 * e + 1;
    const int ilo0 = max(0, D0 - (WW - 1)), ihi0 = min(D0, HH - 1);
    const int ilo1 = max(0, D1 - (WW - 1)), ihi1 = min(D1, HH - 1);  // e=79: empty
    const int sm1 = (D0 - 1) & 3, s0 = D0 & 3, s1 = D1 & 3;

    if (wv < NCW) {
      pfetch(min(e + 1, NINT - 1), xn);          // issue next interval's x early
      const int aw = ilo1 + STRIDE * wv;
      if ((aw - 1 <= ihi0) || (aw <= ihi1)) {    // wave-uniform activity check
        doTile(sm1, s0, aw - 1, ilo0, ihi0, xc[0], false);
        // T0's h-writes must be LDS-visible before T1's cross-lane reads
        __builtin_amdgcn_s_waitcnt(0xC07F);      // lgkmcnt(0) only
        doTile(s0, s1, aw, ilo1, ihi1, xc[1], true);
      }
#pragma unroll
      for (int t = 0; t < 2; ++t)
#pragma unroll
        for (int cb = 0; cb < 4; ++cb) xc[t][cb] = xn[t][cb];
    } else {
      if (D0 >= 2) flushDiag(D0 - 2);
      if (D0 >= 1) flushDiag(D0 - 1);
    }

    // Raw barrier: drain LDS only; vmem (x loads, scratch stores) in flight.
    __builtin_amdgcn_s_waitcnt(0xC07F);          // vmcnt(63) expcnt(7) lgkmcnt(0)
    __builtin_amdgcn_s_barrier();
  }

  // final flush: diag 158 (slot 2); diag "159" never existed
  if (wv >= NCW) flushDiag(NDIAG - 1);
}

// ---------------------------------------------------------------------------
// Reduce: out[b][c][i][j] = sum over 4 dirs of scratch[dir][b][i][j][c].
// ---------------------------------------------------------------------------
__global__ __launch_bounds__(256) void reduce_kernel(const f16* __restrict__ s,
                                                     float* __restrict__ out) {
  const int bi = blockIdx.x;            // b*HH + i
  const int b = bi / HH, i = bi - b * HH;
  __shared__ float tile[WW][CC + 1];    // [j][c], stride 65
  const size_t dstride = (size_t)BB * SLICE;
  const f16* p = s + (size_t)b * SLICE + (size_t)i * (WW * CC);
  for (int idx = threadIdx.x; idx < (WW * CC) / 8; idx += 256) {  // 640
    const int j = idx >> 3, c8 = (idx & 7) * 8;
    const size_t off = (size_t)j * CC + c8;
    const f16x8 a0 = *(const f16x8*)(p + off);
    const f16x8 a1 = *(const f16x8*)(p + off + dstride);
    const f16x8 a2 = *(const f16x8*)(p + off + 2 * dstride);
    const f16x8 a3 = *(const f16x8*)(p + off + 3 * dstride);
#pragma unroll
    for (int k = 0; k < 8; ++k)
      tile[j][c8 + k] = (float)a0[k] + (float)a1[k] + (float)a2[k] + (float)a3[k];
  }
  __syncthreads();
  float* op = out + ((size_t)(b * CC) * HH + i) * WW;  // + c*(H*W) + j
  const int c  = threadIdx.x >> 2;        // 0..63
  const int jb = (threadIdx.x & 3) * 4;   // 0,4,8,12
#pragma unroll
  for (int k = 0; k < 5; ++k) {
    const int j0 = jb + k * 16;
    floatx4 v;
    v[0] = tile[j0 + 0][c];
    v[1] = tile[j0 + 1][c];
    v[2] = tile[j0 + 2][c];
    v[3] = tile[j0 + 3][c];
    *(floatx4*)(op + (size_t)c * (HH * WW) + j0) = v;  // 64B contiguous per 4 lanes
  }
}

// ---------------------------------------------------------------------------
extern "C" void kernel_launch(void* const* d_in, const int* in_sizes, int n_in,
                              void* d_out, int out_size, void* d_ws, size_t ws_size,
                              hipStream_t stream) {
  const float* x = (const float*)d_in[0];
  GPtrs g;
  for (int k = 0; k < 8; ++k) g.p[k] = (const float*)d_in[k + 1];  // g1,g2,g4,g5,g7,g8,g10,g11
  f16* xT = (f16*)d_ws;                         // 26.2 MB
  f16* scratch = xT + (size_t)BB * SLICE;       // 104.9 MB

  xpose_kernel<<<BB * HH, 256, 0, stream>>>(x, xT);
  dag_kernel<<<4 * BB, NTHREADS, 0, stream>>>((const f16*)xT, g, scratch);
  reduce_kernel<<<BB * HH, 256, 0, stream>>>((const f16*)scratch, (float*)d_out);
}